// Round 3
// baseline (475176.514 us; speedup 1.0000x reference)
//
#include <hip/hip_runtime.h>
#include <cstdint>
#include <cstddef>

#define HS 512
#define MBK 100

constexpr int TPB  = 1024;            // 16 waves/block
constexpr int GBLK = 16;
constexpr int OWNB = 1536 / GBLK;     // 96 owned rows per block
constexpr int OWNW = OWNB / 16;       // 6 owned rows per wave

// ---------------- workspace layout (float offsets) ----------------
constexpr size_t OFF_TWwp  = 0;                       // [3][1536]  W_wp^T
constexpr size_t OFF_TWh0  = OFF_TWwp  + 3*1536;      // W_rh[512:1024)^T   (h-part)
constexpr size_t OFF_TWh1  = OFF_TWh0  + 512*512;     // W_rha[2560:3072)^T (ha-part)
constexpr size_t OFF_TWh2  = OFF_TWh1  + 512*512;     // W_rhm[2560:3072)^T (hm-part)
constexpr size_t OFF_TWu0  = OFF_TWh2  + 512*512;     // W_rh[0:512)^T      (r-part)
constexpr size_t OFF_TWu1  = OFF_TWu0  + 512*512;     // W_rha[2048:2560)^T
constexpr size_t OFF_TWu2  = OFF_TWu1  + 512*512;     // W_rhm[2048:2560)^T
constexpr size_t OFF_PAca  = OFF_TWu2  + 512*512;     // [4096][512]
constexpr size_t OFF_PMcm  = OFF_PAca  + 4096*512;
constexpr size_t OFF_PArha = OFF_PMcm  + 4096*512;
constexpr size_t OFF_PMrhm = OFF_PArha + 4096*512;
constexpr size_t OFF_PAwpa = OFF_PMrhm + 4096*512;    // [4096][100]
constexpr size_t OFF_PMwpm = OFF_PAwpa + 4096*100;
constexpr size_t OFF_G     = OFF_PMwpm + 4096*100;    // [1536][128]
constexpr size_t OFF_CARRY = OFF_G     + 1536*128;    // u64[2][1536] tagged {tag,f32}

// ---------------- device helpers ----------------
__device__ __forceinline__ unsigned long long ald(const unsigned long long* p) {
  return __hip_atomic_load(const_cast<unsigned long long*>(p),
                           __ATOMIC_RELAXED, __HIP_MEMORY_SCOPE_AGENT);
}
__device__ __forceinline__ void gstTag(unsigned long long* p, float v, unsigned tag) {
  unsigned long long u = ((unsigned long long)tag << 32) | (unsigned long long)__float_as_uint(v);
  __hip_atomic_store(p, u, __ATOMIC_RELAXED, __HIP_MEMORY_SCOPE_AGENT);
}
__device__ __forceinline__ float xrsum(float v) {
  #pragma unroll
  for (int o = 32; o; o >>= 1) v += __shfl_xor(v, o, 64);
  return v;
}

template<int K4>
__device__ __forceinline__ float dotK(const float* __restrict__ w, const float* x_lds) {
  int l = threadIdx.x & 63;
  const float4* w4 = (const float4*)w;
  const float4* x4 = (const float4*)x_lds;
  float acc = 0.f;
  #pragma unroll
  for (int it = 0; it < K4; ++it) {
    float4 a = w4[l + 64*it];
    float4 b = x4[l + 64*it];
    acc += a.x*b.x + a.y*b.y + a.z*b.z + a.w*b.w;
  }
  return acc;
}

__device__ __forceinline__ void dot2K512(const float* __restrict__ w,
                                         const float* xa, const float* xm,
                                         float& ra, float& rm) {
  int l = threadIdx.x & 63;
  const float4* w4 = (const float4*)w;
  const float4* a4 = (const float4*)xa;
  const float4* m4 = (const float4*)xm;
  float sa = 0.f, sm = 0.f;
  #pragma unroll
  for (int it = 0; it < 2; ++it) {
    float4 wv = w4[l + 64*it], av = a4[l + 64*it], mv = m4[l + 64*it];
    sa += wv.x*av.x + wv.y*av.y + wv.z*av.z + wv.w*av.w;
    sm += wv.x*mv.x + wv.y*mv.y + wv.z*mv.z + wv.w*mv.w;
  }
  #pragma unroll
  for (int o = 32; o; o >>= 1) { sa += __shfl_xor(sa, o, 64); sm += __shfl_xor(sm, o, 64); }
  ra = sa; rm = sm;
}

__device__ __forceinline__ void softmax100_l(const float* g, float* s) {
  int l = threadIdx.x & 63;
  float x1 = g[l];
  float x2 = (l + 64 < 100) ? g[l + 64] : -3.0e38f;
  float m = fmaxf(x1, x2);
  #pragma unroll
  for (int o = 32; o; o >>= 1) m = fmaxf(m, __shfl_xor(m, o, 64));
  float e1 = expf(x1 - m);
  float e2 = (l + 64 < 100) ? expf(x2 - m) : 0.f;
  float ss = e1 + e2;
  #pragma unroll
  for (int o = 32; o; o >>= 1) ss += __shfl_xor(ss, o, 64);
  float inv = 1.f / ss;
  s[l] = e1 * inv;
  if (l + 64 < 100) s[l + 64] = e2 * inv;
}
// softmax over g[i] = p4[i] + p5[i] + brp[i]
__device__ __forceinline__ void softmax_ar(const float* p4, const float* p5,
                                           const float* brp, float* s) {
  int l = threadIdx.x & 63;
  float x1 = p4[l] + p5[l] + brp[l];
  float x2 = (l + 64 < 100) ? (p4[l+64] + p5[l+64] + brp[l+64]) : -3.0e38f;
  float m = fmaxf(x1, x2);
  #pragma unroll
  for (int o = 32; o; o >>= 1) m = fmaxf(m, __shfl_xor(m, o, 64));
  float e1 = expf(x1 - m);
  float e2 = (l + 64 < 100) ? expf(x2 - m) : 0.f;
  float ss = e1 + e2;
  #pragma unroll
  for (int o = 32; o; o >>= 1) ss += __shfl_xor(ss, o, 64);
  float inv = 1.f / ss;
  s[l] = e1 * inv;
  if (l + 64 < 100) s[l + 64] = e2 * inv;
}
__device__ __forceinline__ void softmax3_l(const float* g, float* s) {
  int l = threadIdx.x & 63;
  float x = (l < 3) ? g[l] : -3.0e38f;
  float m = x;
  #pragma unroll
  for (int o = 32; o; o >>= 1) m = fmaxf(m, __shfl_xor(m, o, 64));
  float e = (l < 3) ? expf(x - m) : 0.f;
  float ss = e;
  #pragma unroll
  for (int o = 32; o; o >>= 1) ss += __shfl_xor(ss, o, 64);
  if (l < 3) s[l] = e / ss;
}

// col-per-lane matvec, 256 cols per wave (4/lane), K=512, original [k][512] layout
__device__ __forceinline__ void pass512x4(const float* __restrict__ W,
                                          const float* x, const float* __restrict__ pre,
                                          const float* __restrict__ bias,
                                          float* dst, int cbase) {
  int c = cbase + (threadIdx.x & 63) * 4;
  const float* Wc = W + c;
  float4 acc = {0.f, 0.f, 0.f, 0.f};
  for (int k = 0; k < 512; k += 4) {
    float4 xv = *(const float4*)(x + k);
    float4 w0 = *(const float4*)(Wc + (size_t)(k + 0) * 512);
    float4 w1 = *(const float4*)(Wc + (size_t)(k + 1) * 512);
    float4 w2 = *(const float4*)(Wc + (size_t)(k + 2) * 512);
    float4 w3 = *(const float4*)(Wc + (size_t)(k + 3) * 512);
    acc.x += xv.x*w0.x + xv.y*w1.x + xv.z*w2.x + xv.w*w3.x;
    acc.y += xv.x*w0.y + xv.y*w1.y + xv.z*w2.y + xv.w*w3.y;
    acc.z += xv.x*w0.z + xv.y*w1.z + xv.z*w2.z + xv.w*w3.z;
    acc.w += xv.x*w0.w + xv.y*w1.w + xv.z*w2.w + xv.w*w3.w;
  }
  float4 p = *(const float4*)(pre + c);
  dst[c + 0] = fmaxf(acc.x + p.x + bias[c + 0], 0.f);
  dst[c + 1] = fmaxf(acc.y + p.y + bias[c + 1], 0.f);
  dst[c + 2] = fmaxf(acc.z + p.z + bias[c + 2], 0.f);
  dst[c + 3] = fmaxf(acc.w + p.w + bias[c + 3], 0.f);
}

// col-per-lane, 2 cols/lane, 100-col matrices in original [k][100] layout, k range [k0,k1)
__device__ __forceinline__ float2 passNx2(const float* __restrict__ W,
                                          const float* x, int k0, int k1) {
  int c = (threadIdx.x & 63) * 2;
  float2 acc = {0.f, 0.f};
  if (c < 100) {
    const float* Wc = W + c;
    for (int k = k0; k < k1; k += 2) {
      float2 xv = *(const float2*)(x + k);
      float2 w0 = *(const float2*)(Wc + (size_t)(k + 0) * 100);
      float2 w1 = *(const float2*)(Wc + (size_t)(k + 1) * 100);
      acc.x += xv.x*w0.x + xv.y*w1.x;
      acc.y += xv.x*w0.y + xv.y*w1.y;
    }
  }
  return acc;
}

// ---------------- prep kernels ----------------
__global__ void initK(unsigned long long* carryT, float* G) {
  int i = blockIdx.x * blockDim.x + threadIdx.x, st = gridDim.x * blockDim.x;
  for (int k = i; k < 1536; k += st) carryT[k] = (1ull << 32);    // carry(0)=0, tag 1
  for (int k = i; k < 1536; k += st) carryT[1536 + k] = 0ull;
  for (int k = i; k < 1536 * 128; k += st) G[k] = 0.f;
}

__global__ void transK(const float* __restrict__ src, float* __restrict__ dst, int R, int C) {
  __shared__ float tile[32][33];
  int c0 = blockIdx.x * 32, r0 = blockIdx.y * 32;
  for (int i = threadIdx.y; i < 32; i += 8) {
    int r = r0 + i, c = c0 + threadIdx.x;
    tile[i][threadIdx.x] = (r < R && c < C) ? src[(size_t)r * C + c] : 0.f;
  }
  __syncthreads();
  for (int i = threadIdx.y; i < 32; i += 8) {
    int c = c0 + i, r = r0 + threadIdx.x;
    if (c < C && r < R) dst[(size_t)c * R + r] = tile[threadIdx.x][i];
  }
}

__global__ __launch_bounds__(256) void gemmK(const float* __restrict__ X,
                                             const float* __restrict__ W,
                                             float* __restrict__ C, int N) {
  __shared__ float As[16][68];
  __shared__ float Bs[16][68];
  int t0 = blockIdx.y * 64, n0 = blockIdx.x * 64;
  int tid = threadIdx.x, tx = tid & 15, ty = tid >> 4;
  float acc[4][4] = {};
  for (int k0 = 0; k0 < 2048; k0 += 16) {
    {
      int r = tid >> 2, c = (tid & 3) * 4;
      float4 v = *(const float4*)(X + (size_t)(t0 + r) * 2048 + k0 + c);
      As[c + 0][r] = v.x; As[c + 1][r] = v.y; As[c + 2][r] = v.z; As[c + 3][r] = v.w;
    }
    {
      int kr = tid >> 4, c = (tid & 15) * 4;
      int gcol = n0 + c;
      const float* src = W + (size_t)(k0 + kr) * N + gcol;
      #pragma unroll
      for (int i = 0; i < 4; ++i) Bs[kr][c + i] = (gcol + i < N) ? src[i] : 0.f;
    }
    __syncthreads();
    #pragma unroll
    for (int kk = 0; kk < 16; ++kk) {
      float4 a4 = *(const float4*)&As[kk][ty * 4];
      float4 b4 = *(const float4*)&Bs[kk][tx * 4];
      float av[4] = {a4.x, a4.y, a4.z, a4.w};
      float bv[4] = {b4.x, b4.y, b4.z, b4.w};
      #pragma unroll
      for (int i = 0; i < 4; ++i)
        #pragma unroll
        for (int j = 0; j < 4; ++j) acc[i][j] += av[i] * bv[j];
    }
    __syncthreads();
  }
  #pragma unroll
  for (int i = 0; i < 4; ++i)
    #pragma unroll
    for (int j = 0; j < 4; ++j) {
      int col = n0 + tx * 4 + j;
      if (col < N) C[(size_t)(t0 + ty * 4 + i) * N + col] = acc[i][j];
    }
}

__global__ __launch_bounds__(256) void gemm128(const float* __restrict__ X,
                                               const float* __restrict__ W,
                                               float* __restrict__ C) {
  __shared__ float As[8][132];
  __shared__ float Bs[8][132];
  const int N = 512;
  int t0 = blockIdx.y * 128, n0 = blockIdx.x * 128;
  int tid = threadIdx.x, tx = tid & 15, ty = tid >> 4;
  float acc[8][8] = {};
  for (int k0 = 0; k0 < 2048; k0 += 8) {
    int r = tid >> 1, c4 = (tid & 1) * 4;
    float4 va = *(const float4*)(X + (size_t)(t0 + r) * 2048 + k0 + c4);
    int kr = tid >> 5, cb = (tid & 31) * 4;
    float4 vb = *(const float4*)(W + (size_t)(k0 + kr) * N + n0 + cb);
    __syncthreads();
    As[c4 + 0][r] = va.x; As[c4 + 1][r] = va.y; As[c4 + 2][r] = va.z; As[c4 + 3][r] = va.w;
    Bs[kr][cb] = vb.x; Bs[kr][cb + 1] = vb.y; Bs[kr][cb + 2] = vb.z; Bs[kr][cb + 3] = vb.w;
    __syncthreads();
    #pragma unroll
    for (int kk = 0; kk < 8; ++kk) {
      float av[8], bv[8];
      *(float4*)av       = *(const float4*)&As[kk][ty * 8];
      *(float4*)(av + 4) = *(const float4*)&As[kk][ty * 8 + 4];
      *(float4*)bv       = *(const float4*)&Bs[kk][tx * 8];
      *(float4*)(bv + 4) = *(const float4*)&Bs[kk][tx * 8 + 4];
      #pragma unroll
      for (int i = 0; i < 8; ++i)
        #pragma unroll
        for (int j = 0; j < 8; ++j) acc[i][j] += av[i] * bv[j];
    }
  }
  #pragma unroll
  for (int i = 0; i < 8; ++i) {
    float* dst = C + (size_t)(t0 + ty * 8 + i) * N + n0 + tx * 8;
    *(float4*)dst       = *(float4*)&acc[i][0];
    *(float4*)(dst + 4) = *(float4*)&acc[i][4];
  }
}

// ---------------- persistent recurrence kernel ----------------
struct RArgs {
  const float *TWwp, *TWh0, *TWh1, *TWh2, *TWu0, *TWu1, *TWu2;
  const float *Wca, *Wcm, *Wrp, *Wwpa, *Wwpm;       // original [k][col] layouts
  const float *PAca, *PMcm, *PArha, *PMrhm, *PAwpa, *PMwpm;
  const float *b_ca, *b_cm, *b_wp, *b_wpa, *b_wpm, *b_rp, *b_rh, *b_rha, *b_rhm;
  float *G;
  unsigned long long *carryT;
  float *out;
  int nT;
};

__global__ __launch_bounds__(TPB) void recurK(RArgs a) {
  const int tid  = threadIdx.x;
  const int lane = tid & 63;
  const int lw   = tid >> 6;                 // 0..15
  const int ownBase = blockIdx.x * OWNB;     // 96 rows per block

  __shared__ __align__(16) float s_x[1536];   // carry [ha|hm|h]
  __shared__ __align__(16) float s_bc[1024];  // [ca|cm]  (block-local!)
  __shared__ float s_p4[100], s_p5[100];      // grp partials (k-split)
  __shared__ float s_gwpa[100], s_gwpm[100], s_gwp[4];
  __shared__ float s_ar[104], s_awa[104], s_awm[104], s_aw[8];
  __shared__ float s_part[OWNB];              // Wh·carry partials for owned rows

  for (int t = 0; t < a.nT; ++t) {
    const unsigned tagA = (unsigned)t + 1;

    // ---- stage carry(t): tagged one-shot poll, <=2 slots/thread ----
    {
      const unsigned long long* cin = a.carryT + (size_t)(t & 1) * 1536;
      int i0 = tid, i1 = tid + 1024;
      bool two = (i1 < 1536);
      unsigned long long v0 = ald(cin + i0);
      unsigned long long v1 = two ? ald(cin + i1) : ~0ull;
      while (((unsigned)(v0 >> 32) < tagA) | ((unsigned)(v1 >> 32) < tagA)) {
        __builtin_amdgcn_s_sleep(1);
        v0 = ald(cin + i0);
        if (two) v1 = ald(cin + i1);
      }
      s_x[i0] = __uint_as_float((unsigned)v0);
      if (two) s_x[i1] = __uint_as_float((unsigned)v1);
    }
    __syncthreads();   // #0

    // ---- replicated phase: ca/cm/logits entirely in-block ----
    if (lw == 0) {
      pass512x4(a.Wca, s_x,       a.PAca + (size_t)t * 512, a.b_ca, s_bc,       0);
    } else if (lw == 1) {
      pass512x4(a.Wca, s_x,       a.PAca + (size_t)t * 512, a.b_ca, s_bc,     256);
    } else if (lw == 2) {
      pass512x4(a.Wcm, s_x + 512, a.PMcm + (size_t)t * 512, a.b_cm, s_bc + 512, 0);
    } else if (lw == 3) {
      pass512x4(a.Wcm, s_x + 512, a.PMcm + (size_t)t * 512, a.b_cm, s_bc + 512, 256);
    } else if (lw == 4) {
      float2 p = passNx2(a.Wrp, s_x, 0, 768);
      int c = lane * 2;
      if (c < 100) { s_p4[c] = p.x; s_p4[c + 1] = p.y; }
    } else if (lw == 5) {
      float2 p = passNx2(a.Wrp, s_x, 768, 1536);
      int c = lane * 2;
      if (c < 100) { s_p5[c] = p.x; s_p5[c + 1] = p.y; }
    } else if (lw == 6) {
      float2 p = passNx2(a.Wwpa, s_x, 0, 512);
      int c = lane * 2;
      if (c < 100) {
        s_gwpa[c]     = p.x + a.PAwpa[(size_t)t * 100 + c]     + a.b_wpa[c];
        s_gwpa[c + 1] = p.y + a.PAwpa[(size_t)t * 100 + c + 1] + a.b_wpa[c + 1];
      }
    } else if (lw == 7) {
      float2 p = passNx2(a.Wwpm, s_x + 512, 0, 512);
      int c = lane * 2;
      if (c < 100) {
        s_gwpm[c]     = p.x + a.PMwpm[(size_t)t * 100 + c]     + a.b_wpm[c];
        s_gwpm[c + 1] = p.y + a.PMwpm[(size_t)t * 100 + c + 1] + a.b_wpm[c + 1];
      }
    } else if (lw == 8) {
      #pragma unroll
      for (int c = 0; c < 3; ++c) {
        float v = xrsum(dotK<6>(a.TWwp + (size_t)c * 1536, s_x));
        if (!lane) s_gwp[c] = v + a.b_wp[c];
      }
    } else {
      // waves 9..15: owned Wh·carry partials (block-local), 14 rows each
      int r0 = (lw - 9) * 14;
      for (int i = 0; i < 14; ++i) {
        int rr = r0 + i;
        if (rr >= OWNB) break;
        int q = ownBase + rr;
        int hsel = q >> 9, j = q & 511;           // 0:h 1:ha 2:hm (round-2 decode)
        const float* w  = (hsel == 0) ? a.TWh0 : (hsel == 1) ? a.TWh1 : a.TWh2;
        const float* xs = s_x + ((hsel == 0) ? 1024 : (hsel == 1) ? 0 : 512);
        float v = xrsum(dotK<2>(w + (size_t)j * 512, xs));
        if (!lane) s_part[rr] = v;
      }
    }
    __syncthreads();   // #1

    // ---- replicated softmaxes ----
    if      (lw == 0) softmax_ar(s_p4, s_p5, a.b_rp, s_ar);
    else if (lw == 1) softmax100_l(s_gwpa, s_awa);
    else if (lw == 2) softmax100_l(s_gwpm, s_awm);
    else if (lw == 3) softmax3_l(s_gwp, s_aw);
    __syncthreads();   // #2

    // ---- owned phase: u-dots + G update + contrib + h' + publish carry ----
    const float aw0 = s_aw[0], aw1 = s_aw[1], aw2 = s_aw[2];
    unsigned long long* cout = a.carryT + (size_t)((t + 1) & 1) * 1536;

    #pragma unroll
    for (int i = 0; i < OWNW; ++i) {
      int rr = lw * OWNW + i;
      int q = ownBase + rr;
      int hsel = q >> 9, j = q & 511;
      const float* wu = (hsel == 0) ? a.TWu0 : (hsel == 1) ? a.TWu1 : a.TWu2;
      float uA, uM;
      dot2K512(wu + (size_t)j * 512, s_bc, s_bc + 512, uA, uM);

      float* grow = a.G + (size_t)q * 128;
      int i2 = lane + 64;
      float g1 = grow[lane];
      float g2 = (i2 < 100) ? grow[i2] : 0.f;
      float contrib = s_ar[lane] * g1 + ((i2 < 100) ? s_ar[i2] * g2 : 0.f);
      contrib = xrsum(contrib);
      grow[lane] = aw0 * g1 + aw1 * s_awa[lane] * uA + aw2 * s_awm[lane] * uM;
      if (i2 < 100)
        grow[i2] = aw0 * g2 + aw1 * s_awa[i2] * uA + aw2 * s_awm[i2] * uM;

      if (!lane) {
        float base = s_part[rr];
        if (hsel == 0) {
          float v = fmaxf(contrib + base + a.b_rh[j], 0.f);
          a.out[(size_t)t * 512 + j] = v;
          gstTag(cout + 1024 + j, v, tagA + 1);
        } else if (hsel == 1) {
          float v = fmaxf(contrib + base + a.PArha[(size_t)t * 512 + j] + a.b_rha[j], 0.f);
          gstTag(cout + j, v, tagA + 1);
        } else {
          float v = fmaxf(contrib + base + a.PMrhm[(size_t)t * 512 + j] + a.b_rhm[j], 0.f);
          gstTag(cout + 512 + j, v, tagA + 1);
        }
      }
    }
    // no trailing barrier: next step's staging poll + barrier #0 provide safety
  }
}

// ---------------- host ----------------
extern "C" void kernel_launch(void* const* d_in, const int* in_sizes, int n_in,
                              void* d_out, int out_size, void* d_ws, size_t ws_size,
                              hipStream_t stream) {
  const float* Xa    = (const float*)d_in[0];
  const float* Xm    = (const float*)d_in[1];
  const float* W_ca  = (const float*)d_in[2];  const float* b_ca  = (const float*)d_in[3];
  const float* W_cm  = (const float*)d_in[4];  const float* b_cm  = (const float*)d_in[5];
  const float* W_wp  = (const float*)d_in[6];  const float* b_wp  = (const float*)d_in[7];
  const float* W_wpa = (const float*)d_in[8];  const float* b_wpa = (const float*)d_in[9];
  const float* W_wpm = (const float*)d_in[10]; const float* b_wpm = (const float*)d_in[11];
  const float* W_rp  = (const float*)d_in[12]; const float* b_rp  = (const float*)d_in[13];
  const float* W_rh  = (const float*)d_in[14]; const float* b_rh  = (const float*)d_in[15];
  const float* W_rha = (const float*)d_in[16]; const float* b_rha = (const float*)d_in[17];
  const float* W_rhm = (const float*)d_in[18]; const float* b_rhm = (const float*)d_in[19];

  int nT = out_size / HS;   // 4096
  float* ws = (float*)d_ws;

  initK<<<dim3(256), dim3(256), 0, stream>>>(
      (unsigned long long*)(ws + OFF_CARRY), ws + OFF_G);

  dim3 tb(32, 8);
  auto tg = [](int R, int C) { return dim3((C + 31) / 32, (R + 31) / 32); };
  transK<<<tg(1536, 3),  tb, 0, stream>>>(W_wp,                        ws + OFF_TWwp, 1536, 3);
  transK<<<tg(512, 512), tb, 0, stream>>>(W_rh  + 512 * 512,           ws + OFF_TWh0, 512, 512);
  transK<<<tg(512, 512), tb, 0, stream>>>(W_rha + (size_t)2560 * 512,  ws + OFF_TWh1, 512, 512);
  transK<<<tg(512, 512), tb, 0, stream>>>(W_rhm + (size_t)2560 * 512,  ws + OFF_TWh2, 512, 512);
  transK<<<tg(512, 512), tb, 0, stream>>>(W_rh,                        ws + OFF_TWu0, 512, 512);
  transK<<<tg(512, 512), tb, 0, stream>>>(W_rha + (size_t)2048 * 512,  ws + OFF_TWu1, 512, 512);
  transK<<<tg(512, 512), tb, 0, stream>>>(W_rhm + (size_t)2048 * 512,  ws + OFF_TWu2, 512, 512);

  int tB = nT / 128;
  gemm128<<<dim3(4, tB), dim3(256), 0, stream>>>(Xa, W_ca + (size_t)512 * 512, ws + OFF_PAca);
  gemm128<<<dim3(4, tB), dim3(256), 0, stream>>>(Xm, W_cm + (size_t)512 * 512, ws + OFF_PMcm);
  gemm128<<<dim3(4, tB), dim3(256), 0, stream>>>(Xa, W_rha,                    ws + OFF_PArha);
  gemm128<<<dim3(4, tB), dim3(256), 0, stream>>>(Xm, W_rhm,                    ws + OFF_PMrhm);
  int tB64 = nT / 64;
  gemmK<<<dim3(2, tB64), dim3(256), 0, stream>>>(Xa, W_wpa + (size_t)512 * 100, ws + OFF_PAwpa, 100);
  gemmK<<<dim3(2, tB64), dim3(256), 0, stream>>>(Xm, W_wpm + (size_t)512 * 100, ws + OFF_PMwpm, 100);

  RArgs a;
  a.TWwp = ws + OFF_TWwp;
  a.TWh0 = ws + OFF_TWh0; a.TWh1 = ws + OFF_TWh1; a.TWh2 = ws + OFF_TWh2;
  a.TWu0 = ws + OFF_TWu0; a.TWu1 = ws + OFF_TWu1; a.TWu2 = ws + OFF_TWu2;
  a.Wca = W_ca; a.Wcm = W_cm; a.Wrp = W_rp; a.Wwpa = W_wpa; a.Wwpm = W_wpm;
  a.PAca  = ws + OFF_PAca;  a.PMcm  = ws + OFF_PMcm;
  a.PArha = ws + OFF_PArha; a.PMrhm = ws + OFF_PMrhm;
  a.PAwpa = ws + OFF_PAwpa; a.PMwpm = ws + OFF_PMwpm;
  a.b_ca = b_ca; a.b_cm = b_cm; a.b_wp = b_wp; a.b_wpa = b_wpa; a.b_wpm = b_wpm;
  a.b_rp = b_rp; a.b_rh = b_rh; a.b_rha = b_rha; a.b_rhm = b_rhm;
  a.G      = ws + OFF_G;
  a.carryT = (unsigned long long*)(ws + OFF_CARRY);
  a.out    = (float*)d_out;
  a.nT     = nT;

  recurK<<<dim3(GBLK), dim3(TPB), 0, stream>>>(a);
}

// Round 4
// 27944.608 us; speedup vs baseline: 17.0042x; 17.0042x over previous
//
#include <hip/hip_runtime.h>
#include <cstdint>
#include <cstddef>

#define HS 512

constexpr int TPB  = 512;            // 8 waves/block
constexpr int GBLK = 64;
constexpr int OWNB = 24;             // owned carry rows per block
constexpr int OWNW = 3;              // per wave

// ---------------- workspace layout (float offsets) ----------------
constexpr size_t OFF_TWrp  = 0;                       // [100][1536]
constexpr size_t OFF_TWwp  = OFF_TWrp  + 100*1536;    // [3][1536]
constexpr size_t OFF_TWwpa = OFF_TWwp  + 3*1536;      // [100][512]
constexpr size_t OFF_TWwpm = OFF_TWwpa + 100*512;
constexpr size_t OFF_TWca  = OFF_TWwpm + 100*512;     // [512][512]
constexpr size_t OFF_TWcm  = OFF_TWca  + 512*512;
constexpr size_t OFF_TWh0  = OFF_TWcm  + 512*512;     // W_rh[512:1024)^T   (h)
constexpr size_t OFF_TWh1  = OFF_TWh0  + 512*512;     // W_rha[2560:3072)^T (ha)
constexpr size_t OFF_TWh2  = OFF_TWh1  + 512*512;     // W_rhm[2560:3072)^T (hm)
constexpr size_t OFF_TWu0  = OFF_TWh2  + 512*512;     // W_rh[0:512)^T      (r)
constexpr size_t OFF_TWu1  = OFF_TWu0  + 512*512;     // W_rha[2048:2560)^T
constexpr size_t OFF_TWu2  = OFF_TWu1  + 512*512;     // W_rhm[2048:2560)^T
constexpr size_t OFF_PAca  = OFF_TWu2  + 512*512;     // [4096][512]
constexpr size_t OFF_PMcm  = OFF_PAca  + 4096*512;
constexpr size_t OFF_PArha = OFF_PMcm  + 4096*512;
constexpr size_t OFF_PMrhm = OFF_PArha + 4096*512;
constexpr size_t OFF_PAwpa = OFF_PMrhm + 4096*512;    // [4096][100]
constexpr size_t OFF_PMwpm = OFF_PAwpa + 4096*100;
constexpr size_t OFF_CARRY = OFF_PMwpm + 4096*100;    // u64[2][1536] tagged
constexpr size_t OFF_BCAST = OFF_CARRY + 2*1536*2;    // u64[2][1344] tagged
// bcast: [0:512) ca  [512:1024) cm  [1024:1124) grp  [1124:1224) gwpa
//        [1224:1324) gwpm  [1324:1327) wp

// ---------------- device helpers ----------------
__device__ __forceinline__ unsigned long long ald(const unsigned long long* p) {
  return __hip_atomic_load(const_cast<unsigned long long*>(p),
                           __ATOMIC_RELAXED, __HIP_MEMORY_SCOPE_AGENT);
}
__device__ __forceinline__ void gstTag(unsigned long long* p, float v, unsigned tag) {
  unsigned long long u = ((unsigned long long)tag << 32) | (unsigned long long)__float_as_uint(v);
  __hip_atomic_store(p, u, __ATOMIC_RELAXED, __HIP_MEMORY_SCOPE_AGENT);
}
__device__ __forceinline__ float xrsum(float v) {
  #pragma unroll
  for (int o = 32; o; o >>= 1) v += __shfl_xor(v, o, 64);
  return v;
}

template<int K4>
__device__ __forceinline__ float dotK(const float* __restrict__ w, const float* x) {
  int l = threadIdx.x & 63;
  const float4* w4 = (const float4*)w;
  const float4* x4 = (const float4*)x;
  float acc = 0.f;
  #pragma unroll
  for (int it = 0; it < K4; ++it) {
    float4 a = w4[l + 64*it];
    float4 b = x4[l + 64*it];
    acc += a.x*b.x + a.y*b.y + a.z*b.z + a.w*b.w;
  }
  return acc;
}

__device__ __forceinline__ void dot2K512(const float* __restrict__ w,
                                         const float* xa, const float* xm,
                                         float& ra, float& rm) {
  int l = threadIdx.x & 63;
  const float4* w4 = (const float4*)w;
  const float4* a4 = (const float4*)xa;
  const float4* m4 = (const float4*)xm;
  float sa = 0.f, sm = 0.f;
  #pragma unroll
  for (int it = 0; it < 2; ++it) {
    float4 wv = w4[l + 64*it], av = a4[l + 64*it], mv = m4[l + 64*it];
    sa += wv.x*av.x + wv.y*av.y + wv.z*av.z + wv.w*av.w;
    sm += wv.x*mv.x + wv.y*mv.y + wv.z*mv.z + wv.w*mv.w;
  }
  #pragma unroll
  for (int o = 32; o; o >>= 1) { sa += __shfl_xor(sa, o, 64); sm += __shfl_xor(sm, o, 64); }
  ra = sa; rm = sm;
}

// ---------------- prep kernels ----------------
__global__ void initK(unsigned long long* carryT, unsigned long long* bcast) {
  int i = blockIdx.x * blockDim.x + threadIdx.x, st = gridDim.x * blockDim.x;
  for (int k = i; k < 1536; k += st) carryT[k] = (1ull << 32);   // carry(0)=0, tag 1
  for (int k = i; k < 1536; k += st) carryT[1536 + k] = 0ull;
  for (int k = i; k < 2 * 1344; k += st) bcast[k] = 0ull;
}

__global__ void transK(const float* __restrict__ src, float* __restrict__ dst, int R, int C) {
  __shared__ float tile[32][33];
  int c0 = blockIdx.x * 32, r0 = blockIdx.y * 32;
  for (int i = threadIdx.y; i < 32; i += 8) {
    int r = r0 + i, c = c0 + threadIdx.x;
    tile[i][threadIdx.x] = (r < R && c < C) ? src[(size_t)r * C + c] : 0.f;
  }
  __syncthreads();
  for (int i = threadIdx.y; i < 32; i += 8) {
    int c = c0 + i, r = r0 + threadIdx.x;
    if (c < C && r < R) dst[(size_t)c * R + r] = tile[threadIdx.x][i];
  }
}

__global__ __launch_bounds__(256) void gemmK(const float* __restrict__ X,
                                             const float* __restrict__ W,
                                             float* __restrict__ C, int N) {
  __shared__ float As[16][68];
  __shared__ float Bs[16][68];
  int t0 = blockIdx.y * 64, n0 = blockIdx.x * 64;
  int tid = threadIdx.x, tx = tid & 15, ty = tid >> 4;
  float acc[4][4] = {};
  for (int k0 = 0; k0 < 2048; k0 += 16) {
    {
      int r = tid >> 2, c = (tid & 3) * 4;
      float4 v = *(const float4*)(X + (size_t)(t0 + r) * 2048 + k0 + c);
      As[c + 0][r] = v.x; As[c + 1][r] = v.y; As[c + 2][r] = v.z; As[c + 3][r] = v.w;
    }
    {
      int kr = tid >> 4, c = (tid & 15) * 4;
      int gcol = n0 + c;
      const float* src = W + (size_t)(k0 + kr) * N + gcol;
      #pragma unroll
      for (int i = 0; i < 4; ++i) Bs[kr][c + i] = (gcol + i < N) ? src[i] : 0.f;
    }
    __syncthreads();
    #pragma unroll
    for (int kk = 0; kk < 16; ++kk) {
      float4 a4 = *(const float4*)&As[kk][ty * 4];
      float4 b4 = *(const float4*)&Bs[kk][tx * 4];
      float av[4] = {a4.x, a4.y, a4.z, a4.w};
      float bv[4] = {b4.x, b4.y, b4.z, b4.w};
      #pragma unroll
      for (int i = 0; i < 4; ++i)
        #pragma unroll
        for (int j = 0; j < 4; ++j) acc[i][j] += av[i] * bv[j];
    }
    __syncthreads();
  }
  #pragma unroll
  for (int i = 0; i < 4; ++i)
    #pragma unroll
    for (int j = 0; j < 4; ++j) {
      int col = n0 + tx * 4 + j;
      if (col < N) C[(size_t)(t0 + ty * 4 + i) * N + col] = acc[i][j];
    }
}

__global__ __launch_bounds__(256) void gemm128(const float* __restrict__ X,
                                               const float* __restrict__ W,
                                               float* __restrict__ C) {
  __shared__ float As[8][132];
  __shared__ float Bs[8][132];
  const int N = 512;
  int t0 = blockIdx.y * 128, n0 = blockIdx.x * 128;
  int tid = threadIdx.x, tx = tid & 15, ty = tid >> 4;
  float acc[8][8] = {};
  for (int k0 = 0; k0 < 2048; k0 += 8) {
    int r = tid >> 1, c4 = (tid & 1) * 4;
    float4 va = *(const float4*)(X + (size_t)(t0 + r) * 2048 + k0 + c4);
    int kr = tid >> 5, cb = (tid & 31) * 4;
    float4 vb = *(const float4*)(W + (size_t)(k0 + kr) * N + n0 + cb);
    __syncthreads();
    As[c4 + 0][r] = va.x; As[c4 + 1][r] = va.y; As[c4 + 2][r] = va.z; As[c4 + 3][r] = va.w;
    Bs[kr][cb] = vb.x; Bs[kr][cb + 1] = vb.y; Bs[kr][cb + 2] = vb.z; Bs[kr][cb + 3] = vb.w;
    __syncthreads();
    #pragma unroll
    for (int kk = 0; kk < 8; ++kk) {
      float av[8], bv[8];
      *(float4*)av       = *(const float4*)&As[kk][ty * 8];
      *(float4*)(av + 4) = *(const float4*)&As[kk][ty * 8 + 4];
      *(float4*)bv       = *(const float4*)&Bs[kk][tx * 8];
      *(float4*)(bv + 4) = *(const float4*)&Bs[kk][tx * 8 + 4];
      #pragma unroll
      for (int i = 0; i < 8; ++i)
        #pragma unroll
        for (int j = 0; j < 8; ++j) acc[i][j] += av[i] * bv[j];
    }
  }
  #pragma unroll
  for (int i = 0; i < 8; ++i) {
    float* dst = C + (size_t)(t0 + ty * 8 + i) * N + n0 + tx * 8;
    *(float4*)dst       = *(float4*)&acc[i][0];
    *(float4*)(dst + 4) = *(float4*)&acc[i][4];
  }
}

// ---------------- persistent recurrence kernel ----------------
struct RArgs {
  const float *TWrp, *TWwp, *TWwpa, *TWwpm, *TWca, *TWcm;
  const float *TWh0, *TWh1, *TWh2, *TWu0, *TWu1, *TWu2;
  const float *PAca, *PMcm, *PArha, *PMrhm, *PAwpa, *PMwpm;
  const float *b_ca, *b_cm, *b_wp, *b_wpa, *b_wpm, *b_rp, *b_rh, *b_rha, *b_rhm;
  unsigned long long *carryT, *bcast;
  float *out;
  int nT;
};

__global__ __launch_bounds__(TPB, 1) void recurK(RArgs a) {
  const int tid  = threadIdx.x;
  const int lane = tid & 63;
  const int lw   = tid >> 6;                 // 0..7
  const int b    = blockIdx.x;

  // ---- LDS (~121 KB static; gfx950 allows 160 KB/WG) ----
  __shared__ __align__(16) float s_wca[8 * 512];     // ca rows (cols b*8..b*8+7)
  __shared__ __align__(16) float s_wcm[8 * 512];
  __shared__ __align__(16) float s_wbig[2 * 1536];   // grp / wp rows
  __shared__ __align__(16) float s_wsm[4 * 512];     // gwpa / gwpm rows
  __shared__ __align__(16) float s_TWu[OWNB * 512];  // owned u-rows
  __shared__ float s_G[OWNB * 104];                  // block-private G (LDS-resident)
  __shared__ __align__(16) float s_x[1536];          // carry [ha|hm|h]
  __shared__ __align__(16) float s_c[1024];          // [ca|cm]
  __shared__ float s_ar[104], s_awa[104], s_awm[104], s_aw[4];
  __shared__ float s_part[OWNB];

  // ---- static assignment maps ----
  const int r0a = (b + 51) & 63;                 // gwpa rows r0a, r0a+64(if<36)
  const int r1m = (b + 25) & 63;                 // gwpm rows
  const bool big1_grp = (b < 36);
  const bool big1_wp  = (b >= 40 && b <= 42);

  // ---- stage weights into LDS (once) ----
  for (int i = tid; i < 8 * 512; i += TPB) {
    int row = i >> 9, col = i & 511;
    s_wca[i] = a.TWca[(size_t)(b * 8 + row) * 512 + col];
    s_wcm[i] = a.TWcm[(size_t)(b * 8 + row) * 512 + col];
  }
  for (int i = tid; i < 1536; i += TPB) {
    s_wbig[i] = a.TWrp[(size_t)b * 1536 + i];
    float v2 = 0.f;
    if (big1_grp)      v2 = a.TWrp[(size_t)(b + 64) * 1536 + i];
    else if (big1_wp)  v2 = a.TWwp[(size_t)(b - 40) * 1536 + i];
    s_wbig[1536 + i] = v2;
  }
  for (int i = tid; i < 512; i += TPB) {
    s_wsm[i]        = a.TWwpa[(size_t)r0a * 512 + i];
    s_wsm[512 + i]  = (r0a < 36) ? a.TWwpa[(size_t)(r0a + 64) * 512 + i] : 0.f;
    s_wsm[1024 + i] = a.TWwpm[(size_t)r1m * 512 + i];
    s_wsm[1536 + i] = (r1m < 36) ? a.TWwpm[(size_t)(r1m + 64) * 512 + i] : 0.f;
  }
  for (int i = tid; i < OWNB * 512; i += TPB) {
    int rr = i >> 9, col = i & 511;
    int q = b * OWNB + rr, hsel = q >> 9, j = q & 511;
    const float* src = (hsel == 0) ? a.TWu0 : (hsel == 1) ? a.TWu1 : a.TWu2;
    s_TWu[i] = src[(size_t)j * 512 + col];
  }
  for (int i = tid; i < OWNB * 104; i += TPB) s_G[i] = 0.f;

  // ---- per-wave constants ----
  const int cacol = b * 8 + lw;
  const float bCa = a.b_ca[cacol];
  const float bCm = a.b_cm[cacol];

  // gate job: wave7=big0(grp b), wave6=big1, wave5/4=gwpa, wave3/2=gwpm
  int gtype = 0, gslot = 0, gdst = 0, gxoff = 0;
  const float* gpre = nullptr;      // per-step: gpre[t*100]
  float gbias = 0.f;
  if (lw == 7)      { gtype = 1; gslot = 0; gdst = 1024 + b; gbias = a.b_rp[b]; }
  else if (lw == 6) {
    if (big1_grp)     { gtype = 1; gslot = 1; gdst = 1024 + b + 64; gbias = a.b_rp[b + 64]; }
    else if (big1_wp) { gtype = 1; gslot = 1; gdst = 1324 + (b - 40); gbias = a.b_wp[b - 40]; }
  }
  else if (lw == 5) { gtype = 2; gslot = 0; gdst = 1124 + r0a; gxoff = 0;
                      gpre = a.PAwpa + r0a; gbias = a.b_wpa[r0a]; }
  else if (lw == 4 && r0a < 36) { gtype = 2; gslot = 1; gdst = 1124 + r0a + 64; gxoff = 0;
                      gpre = a.PAwpa + r0a + 64; gbias = a.b_wpa[r0a + 64]; }
  else if (lw == 3) { gtype = 2; gslot = 2; gdst = 1224 + r1m; gxoff = 512;
                      gpre = a.PMwpm + r1m; gbias = a.b_wpm[r1m]; }
  else if (lw == 2 && r1m < 36) { gtype = 2; gslot = 3; gdst = 1224 + r1m + 64; gxoff = 512;
                      gpre = a.PMwpm + r1m + 64; gbias = a.b_wpm[r1m + 64]; }

  // owned rows
  int ownHsel[OWNW], ownJ[OWNW], whX[OWNW];
  float ownBias[OWNW];
  const float* ownPre[OWNW];
  const float* whRow[OWNW];
  #pragma unroll
  for (int k = 0; k < OWNW; ++k) {
    int q = b * OWNB + lw * OWNW + k, hsel = q >> 9, j = q & 511;
    ownHsel[k] = hsel; ownJ[k] = j;
    if (hsel == 0)      { ownBias[k] = a.b_rh[j];  ownPre[k] = nullptr;
                          whRow[k] = a.TWh0 + (size_t)j * 512; whX[k] = 1024; }
    else if (hsel == 1) { ownBias[k] = a.b_rha[j]; ownPre[k] = a.PArha + j;
                          whRow[k] = a.TWh1 + (size_t)j * 512; whX[k] = 0; }
    else                { ownBias[k] = a.b_rhm[j]; ownPre[k] = a.PMrhm + j;
                          whRow[k] = a.TWh2 + (size_t)j * 512; whX[k] = 512; }
  }
  __syncthreads();

  // ---------------- time loop ----------------
  for (int t = 0; t < a.nT; ++t) {
    const unsigned tagB = (unsigned)t + 1;
    unsigned long long* bc = a.bcast + (size_t)(t & 1) * 1344;

    // prefetch per-step scalars (land during carry poll)
    float preCa = a.PAca[(size_t)t * 512 + cacol];
    float preCm = a.PMcm[(size_t)t * 512 + cacol];
    float preG  = (gtype == 2) ? gpre[(size_t)t * 100] : 0.f;
    float preO[OWNW];
    #pragma unroll
    for (int k = 0; k < OWNW; ++k)
      preO[k] = ownPre[k] ? ownPre[k][(size_t)t * 512] : 0.f;

    // ---- poll carry(t): 3 slots/thread ----
    {
      const unsigned long long* cin = a.carryT + (size_t)(t & 1) * 1536;
      int i0 = tid, i1 = tid + 512, i2 = tid + 1024;
      unsigned long long v0 = ald(cin + i0), v1 = ald(cin + i1), v2 = ald(cin + i2);
      while (((unsigned)(v0 >> 32) < tagB) | ((unsigned)(v1 >> 32) < tagB) |
             ((unsigned)(v2 >> 32) < tagB)) {
        __builtin_amdgcn_s_sleep(1);
        v0 = ald(cin + i0); v1 = ald(cin + i1); v2 = ald(cin + i2);
      }
      s_x[i0] = __uint_as_float((unsigned)v0);
      s_x[i1] = __uint_as_float((unsigned)v1);
      s_x[i2] = __uint_as_float((unsigned)v2);
    }
    __syncthreads();   // SYNC0

    // ---- phase A: gate job first (critical for other blocks' softmax) ----
    if (gtype == 1) {
      float v = xrsum(dotK<6>(s_wbig + gslot * 1536, s_x));
      if (!lane) gstTag(bc + gdst, v + gbias, tagB);
    } else if (gtype == 2) {
      float v = xrsum(dotK<2>(s_wsm + gslot * 512, s_x + gxoff));
      if (!lane) gstTag(bc + gdst, v + gbias + preG, tagB);
    }
    {
      float v = xrsum(dotK<2>(s_wca + lw * 512, s_x));
      if (!lane) gstTag(bc + cacol, fmaxf(v + preCa + bCa, 0.f), tagB);
      v = xrsum(dotK<2>(s_wcm + lw * 512, s_x + 512));
      if (!lane) gstTag(bc + 512 + cacol, fmaxf(v + preCm + bCm, 0.f), tagB);
    }
    // TWh parts from L2 (off the inter-block critical path)
    #pragma unroll
    for (int k = 0; k < OWNW; ++k) {
      float v = xrsum(dotK<2>(whRow[k], s_x + whX[k]));
      if (!lane) s_part[lw * OWNW + k] = v;
    }

    // ---- phase B polls: waves 0-3 softmax groups (reg-direct), waves 4-7 c ----
    if (lw < 3) {
      int base = 1024 + lw * 100;       // grp / gwpa / gwpm
      const unsigned long long* p1 = bc + base + lane;
      bool two = lane < 36;
      unsigned long long v1 = ald(p1);
      unsigned long long v2 = two ? ald(p1 + 64) : ~0ull;
      while (((unsigned)(v1 >> 32) < tagB) | ((unsigned)(v2 >> 32) < tagB)) {
        __builtin_amdgcn_s_sleep(1);
        v1 = ald(p1); if (two) v2 = ald(p1 + 64);
      }
      float x1 = __uint_as_float((unsigned)v1);
      float x2 = two ? __uint_as_float((unsigned)v2) : -3.0e38f;
      float m = fmaxf(x1, x2);
      #pragma unroll
      for (int o = 32; o; o >>= 1) m = fmaxf(m, __shfl_xor(m, o, 64));
      float e1 = expf(x1 - m);
      float e2 = two ? expf(x2 - m) : 0.f;
      float ss = e1 + e2;
      #pragma unroll
      for (int o = 32; o; o >>= 1) ss += __shfl_xor(ss, o, 64);
      float inv = 1.f / ss;
      float* dst = (lw == 0) ? s_ar : (lw == 1) ? s_awa : s_awm;
      dst[lane] = e1 * inv;
      if (two) dst[64 + lane] = e2 * inv;
    } else if (lw == 3) {
      float x = -3.0e38f;
      if (lane < 3) {
        const unsigned long long* p = bc + 1324 + lane;
        unsigned long long v = ald(p);
        while ((unsigned)(v >> 32) < tagB) { __builtin_amdgcn_s_sleep(1); v = ald(p); }
        x = __uint_as_float((unsigned)v);
      }
      float m = x;
      #pragma unroll
      for (int o = 32; o; o >>= 1) m = fmaxf(m, __shfl_xor(m, o, 64));
      float e = (lane < 3) ? expf(x - m) : 0.f;
      float ss = e;
      #pragma unroll
      for (int o = 32; o; o >>= 1) ss += __shfl_xor(ss, o, 64);
      if (lane < 3) s_aw[lane] = e / ss;
    } else {
      int base = tid - 256;              // 0..255, 4 slots each
      const unsigned long long* p = bc + base;
      unsigned long long v0 = ald(p), v1 = ald(p + 256), v2 = ald(p + 512), v3 = ald(p + 768);
      while (((unsigned)(v0 >> 32) < tagB) | ((unsigned)(v1 >> 32) < tagB) |
             ((unsigned)(v2 >> 32) < tagB) | ((unsigned)(v3 >> 32) < tagB)) {
        __builtin_amdgcn_s_sleep(1);
        v0 = ald(p); v1 = ald(p + 256); v2 = ald(p + 512); v3 = ald(p + 768);
      }
      s_c[base]       = __uint_as_float((unsigned)v0);
      s_c[base + 256] = __uint_as_float((unsigned)v1);
      s_c[base + 512] = __uint_as_float((unsigned)v2);
      s_c[base + 768] = __uint_as_float((unsigned)v3);
    }
    __syncthreads();   // SYNC1

    // ---- owned phase: u-dots + G(LDS) + h' + publish carry(t+1) ----
    const float aw0 = s_aw[0], aw1 = s_aw[1], aw2 = s_aw[2];
    unsigned long long* cout = a.carryT + (size_t)((t + 1) & 1) * 1536;
    #pragma unroll
    for (int k = 0; k < OWNW; ++k) {
      int rr = lw * OWNW + k;
      float uA, uM;
      dot2K512(s_TWu + (size_t)rr * 512, s_c, s_c + 512, uA, uM);

      float* grow = s_G + rr * 104;
      bool two = lane < 36;
      float g1 = grow[lane];
      float g2 = two ? grow[64 + lane] : 0.f;
      float contrib = s_ar[lane] * g1 + (two ? s_ar[64 + lane] * g2 : 0.f);
      contrib = xrsum(contrib);
      grow[lane] = aw0 * g1 + aw1 * s_awa[lane] * uA + aw2 * s_awm[lane] * uM;
      if (two)
        grow[64 + lane] = aw0 * g2 + aw1 * s_awa[64 + lane] * uA + aw2 * s_awm[64 + lane] * uM;

      if (!lane) {
        int j = ownJ[k];
        float h = fmaxf(contrib + s_part[rr] + preO[k] + ownBias[k], 0.f);
        if (ownHsel[k] == 0) {
          a.out[(size_t)t * 512 + j] = h;
          gstTag(cout + 1024 + j, h, tagB + 1);
        } else if (ownHsel[k] == 1) {
          gstTag(cout + j, h, tagB + 1);
        } else {
          gstTag(cout + 512 + j, h, tagB + 1);
        }
      }
    }
    __syncthreads();   // SYNC2: protect s_x/s_c/s_ar/s_aw for next step
  }
}

// ---------------- host ----------------
extern "C" void kernel_launch(void* const* d_in, const int* in_sizes, int n_in,
                              void* d_out, int out_size, void* d_ws, size_t ws_size,
                              hipStream_t stream) {
  const float* Xa    = (const float*)d_in[0];
  const float* Xm    = (const float*)d_in[1];
  const float* W_ca  = (const float*)d_in[2];  const float* b_ca  = (const float*)d_in[3];
  const float* W_cm  = (const float*)d_in[4];  const float* b_cm  = (const float*)d_in[5];
  const float* W_wp  = (const float*)d_in[6];  const float* b_wp  = (const float*)d_in[7];
  const float* W_wpa = (const float*)d_in[8];  const float* b_wpa = (const float*)d_in[9];
  const float* W_wpm = (const float*)d_in[10]; const float* b_wpm = (const float*)d_in[11];
  const float* W_rp  = (const float*)d_in[12]; const float* b_rp  = (const float*)d_in[13];
  const float* W_rh  = (const float*)d_in[14]; const float* b_rh  = (const float*)d_in[15];
  const float* W_rha = (const float*)d_in[16]; const float* b_rha = (const float*)d_in[17];
  const float* W_rhm = (const float*)d_in[18]; const float* b_rhm = (const float*)d_in[19];

  int nT = out_size / HS;   // 4096
  float* ws = (float*)d_ws;

  initK<<<dim3(64), dim3(256), 0, stream>>>(
      (unsigned long long*)(ws + OFF_CARRY),
      (unsigned long long*)(ws + OFF_BCAST));

  dim3 tb(32, 8);
  auto tg = [](int R, int C) { return dim3((C + 31) / 32, (R + 31) / 32); };
  transK<<<tg(1536, 100), tb, 0, stream>>>(W_rp,                       ws + OFF_TWrp,  1536, 100);
  transK<<<tg(1536, 3),   tb, 0, stream>>>(W_wp,                       ws + OFF_TWwp,  1536, 3);
  transK<<<tg(512, 100),  tb, 0, stream>>>(W_wpa,                      ws + OFF_TWwpa, 512, 100);
  transK<<<tg(512, 100),  tb, 0, stream>>>(W_wpm,                      ws + OFF_TWwpm, 512, 100);
  transK<<<tg(512, 512),  tb, 0, stream>>>(W_ca,                       ws + OFF_TWca,  512, 512);
  transK<<<tg(512, 512),  tb, 0, stream>>>(W_cm,                       ws + OFF_TWcm,  512, 512);
  transK<<<tg(512, 512),  tb, 0, stream>>>(W_rh  + 512 * 512,          ws + OFF_TWh0,  512, 512);
  transK<<<tg(512, 512),  tb, 0, stream>>>(W_rha + (size_t)2560 * 512, ws + OFF_TWh1,  512, 512);
  transK<<<tg(512, 512),  tb, 0, stream>>>(W_rhm + (size_t)2560 * 512, ws + OFF_TWh2,  512, 512);
  transK<<<tg(512, 512),  tb, 0, stream>>>(W_rh,                       ws + OFF_TWu0,  512, 512);
  transK<<<tg(512, 512),  tb, 0, stream>>>(W_rha + (size_t)2048 * 512, ws + OFF_TWu1,  512, 512);
  transK<<<tg(512, 512),  tb, 0, stream>>>(W_rhm + (size_t)2048 * 512, ws + OFF_TWu2,  512, 512);

  int tB = nT / 128;
  gemm128<<<dim3(4, tB), dim3(256), 0, stream>>>(Xa, W_ca + (size_t)512 * 512, ws + OFF_PAca);
  gemm128<<<dim3(4, tB), dim3(256), 0, stream>>>(Xm, W_cm + (size_t)512 * 512, ws + OFF_PMcm);
  gemm128<<<dim3(4, tB), dim3(256), 0, stream>>>(Xa, W_rha,                    ws + OFF_PArha);
  gemm128<<<dim3(4, tB), dim3(256), 0, stream>>>(Xm, W_rhm,                    ws + OFF_PMrhm);
  int tB64 = nT / 64;
  gemmK<<<dim3(2, tB64), dim3(256), 0, stream>>>(Xa, W_wpa + (size_t)512 * 100, ws + OFF_PAwpa, 100);
  gemmK<<<dim3(2, tB64), dim3(256), 0, stream>>>(Xm, W_wpm + (size_t)512 * 100, ws + OFF_PMwpm, 100);

  RArgs a;
  a.TWrp  = ws + OFF_TWrp;  a.TWwp  = ws + OFF_TWwp;
  a.TWwpa = ws + OFF_TWwpa; a.TWwpm = ws + OFF_TWwpm;
  a.TWca  = ws + OFF_TWca;  a.TWcm  = ws + OFF_TWcm;
  a.TWh0  = ws + OFF_TWh0;  a.TWh1  = ws + OFF_TWh1;  a.TWh2 = ws + OFF_TWh2;
  a.TWu0  = ws + OFF_TWu0;  a.TWu1  = ws + OFF_TWu1;  a.TWu2 = ws + OFF_TWu2;
  a.PAca  = ws + OFF_PAca;  a.PMcm  = ws + OFF_PMcm;
  a.PArha = ws + OFF_PArha; a.PMrhm = ws + OFF_PMrhm;
  a.PAwpa = ws + OFF_PAwpa; a.PMwpm = ws + OFF_PMwpm;
  a.b_ca = b_ca; a.b_cm = b_cm; a.b_wp = b_wp; a.b_wpa = b_wpa; a.b_wpm = b_wpm;
  a.b_rp = b_rp; a.b_rh = b_rh; a.b_rha = b_rha; a.b_rhm = b_rhm;
  a.carryT = (unsigned long long*)(ws + OFF_CARRY);
  a.bcast  = (unsigned long long*)(ws + OFF_BCAST);
  a.out    = (float*)d_out;
  a.nT     = nT;

  recurK<<<dim3(GBLK), dim3(TPB), 0, stream>>>(a);
}